// Round 14
// baseline (58.325 us; speedup 1.0000x reference)
//
#include <hip/hip_runtime.h>
#include <math.h>

#define B_ 32
#define N_ 2048
#define D_ 512
#define K_ 128
#define GAMMA_ 10.0f
#define EPS_ 1e-12f
#define STEPS_ 10
#define SHIFT_ 18.0f
#define EXP_NEG_SHIFT_ 1.5229979e-08f  // exp(-18)

typedef _Float16 f16x8 __attribute__((ext_vector_type(8)));
typedef float f32x8 __attribute__((ext_vector_type(8)));
typedef float f32x16 __attribute__((ext_vector_type(16)));

__device__ __forceinline__ void gload_lds16(const float4* g, float* l) {
    __builtin_amdgcn_global_load_lds((const __attribute__((address_space(1))) void*)g,
                                     (__attribute__((address_space(3))) void*)l, 16, 0, 0);
}

// ---------------- k1: quantize t to f16 in MFMA-fragment-contiguous layout ----------------
// unit u (16B = 8 f16) = (c*8 + s)*128 + k   where c = d>>6, s = (d&63)>>3
__global__ void k_prep_t(const float* __restrict__ ts, _Float16* __restrict__ tq,
                         float* __restrict__ rt, float* __restrict__ tnn) {
    int k = blockIdx.x;      // 128
    int lane = threadIdx.x;  // 64
    const float4* rp = (const float4*)(ts + (size_t)k * D_ + lane * 8);
    float4 v0 = rp[0], v1 = rp[1];
    f16x8 hv;
    hv[0] = (_Float16)v0.x; hv[1] = (_Float16)v0.y; hv[2] = (_Float16)v0.z; hv[3] = (_Float16)v0.w;
    hv[4] = (_Float16)v1.x; hv[5] = (_Float16)v1.y; hv[6] = (_Float16)v1.z; hv[7] = (_Float16)v1.w;
    float ssq = 0.f;
#pragma unroll
    for (int j = 0; j < 8; ++j) { float x = (float)hv[j]; ssq += x * x; }
#pragma unroll
    for (int off = 32; off; off >>= 1) ssq += __shfl_xor(ssq, off);
    if (lane == 0) {
        float rtv = (float)(1.0 / sqrt((double)ssq + 1e-12));
        rt[k] = rtv;
        tnn[k] = ssq * rtv * rtv;
    }
    *(f16x8*)&tq[((size_t)lane * 128 + k) * 8] = hv;
}

// ---------------- k2: MFMA GEMM + exp epilogue + fused column sums ----------------
// tile: 128 k x 32 n, D chunked by 64, grid = B*64 = 2048 blocks
// features staged via global_load_lds (f32 in LDS, pair-swizzled source);
// A (t) fragments register-prefetched from global (L2)
__global__ __launch_bounds__(256, 6) void k_gemm(
    const float* __restrict__ features,  // [B][N][D] f32
    const _Float16* __restrict__ tq,     // frag-contiguous f16
    const float* __restrict__ rt, const float* __restrict__ tnn,
    _Float16* __restrict__ E,            // [B][K][N] f16, SHIFTED by exp(+18)
    float* __restrict__ A1)              // [B][N], shifted colsums
{
    __shared__ float Bf32[2][32 * 64];   // 2 x 8 KB double-buffered f tile (f32)
    __shared__ float csum[4][32];
    __shared__ float ldsrt[128], ldstnn[128];

    const int tid = threadIdx.x;
    const int b = blockIdx.x >> 6;
    const int n0 = (blockIdx.x & 63) * 32;
    const int w = tid >> 6;       // wave id: k rows [w*32, w*32+32)
    const int l = tid & 63;
    const int hi = l >> 5;
    const int l31 = l & 31;

    if (tid < 128) { ldsrt[tid] = rt[tid]; ldstnn[tid] = tnn[tid]; }

    const float4* fbase = (const float4*)(features + ((size_t)(b * N_ + n0)) * D_);

    // staging geometry (per wave w, issue j): lds 16B-unit o = w*128 + j*64 + l
    // row r = o>>4, stored slot q' = o&15, source slot qsrc = q' ^ ((r&7)<<1)
    const int o0 = w * 128 + l;          // j=0 unit
    const int r0s = o0 >> 4, q0s = (o0 & 15) ^ ((r0s & 7) << 1);
    const int o1 = o0 + 64;              // j=1 unit
    const int r1s = o1 >> 4, q1s = (o1 & 15) ^ ((r1s & 7) << 1);

    float ss = 0.f;                      // raw-f32 partial sumsq of row l31 (hi-half slots)
    f32x16 acc;
#pragma unroll
    for (int i = 0; i < 16; ++i) acc[i] = 0.f;

    f16x8 apre[4];                       // register-prefetched A fragments

    auto stage = [&](int c, int buf) {
        gload_lds16(fbase + (size_t)r0s * 128 + c * 16 + q0s, &Bf32[buf][o0 * 4]);
        gload_lds16(fbase + (size_t)r1s * 128 + c * 16 + q1s, &Bf32[buf][o1 * 4]);
    };

    auto a_load = [&](int c) {
#pragma unroll
        for (int ks = 0; ks < 4; ++ks) {
            int sB = ks * 2 + hi;
            size_t u = (size_t)(c * 8 + sB) * 128 + w * 32 + l31;
            apre[ks] = *(const f16x8*)&tq[u * 8];
        }
    };

    auto compute = [&](int cur) {
#pragma unroll
        for (int ks = 0; ks < 4; ++ks) {
            int sB = ks * 2 + hi;
            int sp = sB ^ (l31 & 7);     // swizzled 32B slot
            f32x8 braw = *(const f32x8*)&Bf32[cur][l31 * 64 + sp * 8];
            f16x8 bfr;
#pragma unroll
            for (int i = 0; i < 8; ++i) {
                ss += braw[i] * braw[i];
                bfr[i] = (_Float16)braw[i];
            }
            acc = __builtin_amdgcn_mfma_f32_32x32x16_f16(apre[ks], bfr, acc, 0, 0, 0);
        }
    };

    stage(0, 0);
    a_load(0);
    __syncthreads();                     // drains stage loads (vmcnt 0 before barrier)

#pragma unroll
    for (int c = 0; c < 8; ++c) {
        int cur = c & 1;
        if (c < 7) stage(c + 1, cur ^ 1);   // async next-chunk stage
        compute(cur);                        // ds_read + cvt + ssq + MFMA
        if (c < 7) a_load(c + 1);            // A prefetch (L2)
        __syncthreads();
    }

    // ---- epilogue ----
    ss += __shfl_xor(ss, 32);            // merge hi halves -> full row-l31 sumsq
    const int n = n0 + l31;
    float rf = (float)(1.0 / sqrt((double)ss + 1e-12));
    float fnn = ss * rf * rf;
    float cs = 0.f;
#pragma unroll
    for (int r = 0; r < 16; ++r) {
        int krow = (r & 3) + 8 * (r >> 2) + 4 * hi;
        int k = w * 32 + krow;
        float cb = ldstnn[k] + fnn - 2.0f * ldsrt[k] * rf * acc[r];
        float e = expf(SHIFT_ - GAMMA_ * cb);   // shifted into f16 normal range
        _Float16 eh = (_Float16)e;
        cs += (float)eh;                        // sum exactly what we store
        E[((size_t)(b * K_ + k)) * N_ + n] = eh;
    }
    cs += __shfl_xor(cs, 32);                   // merge hi-half's k rows
    if (!hi) csum[w][l31] = cs;
    __syncthreads();
    if (tid < 32)
        A1[b * N_ + n0 + tid] = csum[0][tid] + csum[1][tid] + csum[2][tid] + csum[3][tid];
}

// ---------------- k4: collapsed Sinkhorn loop (A0 computed inline) ----------------
__global__ __launch_bounds__(256) void k_sinkhorn(const float* __restrict__ tr,
                                                  const float* __restrict__ c_u,
                                                  const float* __restrict__ A1,
                                                  float* __restrict__ out,
                                                  float* __restrict__ wfb) {
    __shared__ float sc0[4], sc1[4], sres[2];
    int b = blockIdx.x, tid = threadIdx.x;
    float mu = tr[b];
    const float nf = (float)N_;
    float a0[8], a1[8], w[8];
#pragma unroll
    for (int r = 0; r < 8; ++r) {
        int n = tid + 256 * r;
        a0[r] = expf(-GAMMA_ * c_u[b * N_ + n]);
        a1[r] = A1[b * N_ + n] * EXP_NEG_SHIFT_;   // undo global shift exactly in f32
        w[r] = 1.f;
    }
    float alpha = 1.f, beta = 1.f;
    for (int s = 0; s < STEPS_; ++s) {
        float p0 = 0.f, p1 = 0.f;
#pragma unroll
        for (int r = 0; r < 8; ++r) {
            float cs = w[r] * (alpha * a0[r] + beta * a1[r]);
            w[r] = w[r] / (cs * nf + EPS_);
            p0 += a0[r] * w[r];
            p1 += a1[r] * w[r];
        }
#pragma unroll
        for (int off = 32; off; off >>= 1) {
            p0 += __shfl_xor(p0, off);
            p1 += __shfl_xor(p1, off);
        }
        int wid = tid >> 6;
        if ((tid & 63) == 0) { sc0[wid] = p0; sc1[wid] = p1; }
        __syncthreads();
        if (tid == 0) {
            sres[0] = sc0[0] + sc0[1] + sc0[2] + sc0[3];
            sres[1] = sc1[0] + sc1[1] + sc1[2] + sc1[3];
        }
        __syncthreads();
        float s0 = alpha * sres[0], ssum = beta * sres[1];
        alpha *= (1.f - mu) / (s0 + EPS_);
        beta *= mu / (ssum + EPS_);
    }
#pragma unroll
    for (int r = 0; r < 8; ++r) {
        int n = tid + 256 * r;
        float cs = w[r] * (alpha * a0[r] + beta * a1[r]);
        float wf = w[r] / (cs * nf + EPS_);
        out[(size_t)b * (K_ + 1) * N_ + n] = alpha * a0[r] * wf;  // row 0
        wfb[b * N_ + n] = beta * wf * EXP_NEG_SHIFT_;             // fold shift for rows 1..K
    }
}

// ---------------- k5: P rows 1..K = E * wfb ----------------
__global__ void k_scale(const _Float16* __restrict__ E, const float* __restrict__ wfb,
                        float* __restrict__ out) {
    size_t g = (size_t)blockIdx.x * 256 + threadIdx.x;
    size_t idx = g * 8;
    int b = (int)(idx >> 18);            // / (K*N) = 2^18
    int rem = (int)(idx & ((K_ * N_) - 1));
    int k = rem >> 11, n = rem & (N_ - 1);
    f16x8 e = *(const f16x8*)&E[idx];
    float4 w0 = *(const float4*)&wfb[b * N_ + n];
    float4 w1 = *(const float4*)&wfb[b * N_ + n + 4];
    float* op = &out[((size_t)(b * (K_ + 1) + 1 + k)) * N_ + n];
    float4 o0, o1;
    o0.x = (float)e[0] * w0.x; o0.y = (float)e[1] * w0.y;
    o0.z = (float)e[2] * w0.z; o0.w = (float)e[3] * w0.w;
    o1.x = (float)e[4] * w1.x; o1.y = (float)e[5] * w1.y;
    o1.z = (float)e[6] * w1.z; o1.w = (float)e[7] * w1.w;
    *(float4*)op = o0;
    *(float4*)(op + 4) = o1;
}

extern "C" void kernel_launch(void* const* d_in, const int* in_sizes, int n_in,
                              void* d_out, int out_size, void* d_ws, size_t ws_size,
                              hipStream_t stream) {
    const float* features = (const float*)d_in[0];
    const float* tr = (const float*)d_in[1];
    const float* c_u = (const float*)d_in[2];
    const float* ts = (const float*)d_in[3];
    float* out = (float*)d_out;

    char* ws = (char*)d_ws;
    _Float16* tq = (_Float16*)ws;                 // 128*512 f16 = 128 KiB
    float* rt = (float*)(ws + 131072);            // 512 B
    float* tnn = (float*)(ws + 131584);           // 512 B
    float* A1 = (float*)(ws + 132096);            // B*N f32 = 256 KiB
    float* wfb = (float*)(ws + 132096 + 262144);  // 256 KiB
    _Float16* E = (_Float16*)(ws + 132096 + 524288);  // B*K*N f16 = 16 MiB
    (void)in_sizes; (void)n_in; (void)out_size; (void)ws_size;

    k_prep_t<<<K_, 64, 0, stream>>>(ts, tq, rt, tnn);
    k_gemm<<<B_ * 64, 256, 0, stream>>>(features, tq, rt, tnn, E, A1);
    k_sinkhorn<<<B_, 256, 0, stream>>>(tr, c_u, A1, out, wfb);
    k_scale<<<(B_ * K_ * N_) / (8 * 256), 256, 0, stream>>>(E, wfb, out);
}